// Round 4
// baseline (2324.321 us; speedup 1.0000x reference)
//
#include <hip/hip_runtime.h>

// ConvLSTM2D via MFMA implicit-GEMM. B=8,T=16,H=W=64,Cin=32,F=64,3x3 SAME.
// Round 4: K-split occupancy doubling. 512-thread blocks (8 waves):
//   wave = (nq, kh), nq in [0,4) = gate quadruple (N-tiles nq,nq+4,nq+8,nq+12),
//   kh in {0,1} = K-half (k-steps [0,S0) / [S0,NS)).
// Each wave keeps the round-2 shape (4 M-tiles x 4 N-tiles, 16 MFMA/k-step)
// so per-CU LDS-A and L2-B traffic are UNCHANGED while waves/CU double
// (8 -> 16, 4/SIMD) for latency hiding. Partial accs reduced via padded LDS
// exchange; bias folded into kh=0 init only. Loads at use (round-3 explicit
// prefetch regressed: compiler sank loads, VGPR 88->72).
//
// Weights prepacked to B-frag order [s(27)][nt(16)][lane(64)][8] (442 KB,
// L2-resident). h ping-pongs bf16 in ws; c-state fp32 in d_out (t=15
// epilogue replaces c with final h, same-lane RMW).

#define TSTEPS 16

typedef short bf16x8 __attribute__((ext_vector_type(8)));
typedef float f32x4 __attribute__((ext_vector_type(4)));

__device__ __forceinline__ float hsig(float x) {
    return fminf(fmaxf((x + 3.0f) * (1.0f / 6.0f), 0.0f), 1.0f);
}

__device__ __forceinline__ unsigned short f2bf(float f) {
    union { float f; unsigned int u; } v; v.f = f;
    unsigned int r = v.u + 0x7fffu + ((v.u >> 16) & 1u);  // RNE
    return (unsigned short)(r >> 16);
}

// ---- weight prepack: Wg(3,3,32,256), Ug(3,3,64,256) fp32 -> bf16 B-frags ----
__global__ __launch_bounds__(256)
void prepack_w(const float* __restrict__ Wg, const float* __restrict__ Ug,
               unsigned short* __restrict__ out)
{
    int idx = blockIdx.x * 256 + threadIdx.x;   // 27*16*64 = 27648
    if (idx >= 27648) return;
    int lane = idx & 63;
    int nt   = (idx >> 6) & 15;
    int s    = idx >> 10;
    int col = lane & 15, quad = lane >> 4;
    int n = nt * 16 + col;
    int k0 = quad * 8;
    const float* src;
    if (s < 9) {
        src = Wg + ((size_t)s * 32 + k0) * 256 + n;
    } else {
        int ss = s - 9; int tap = ss >> 1; int half = ss & 1;
        src = Ug + ((size_t)tap * 64 + half * 32 + k0) * 256 + n;
    }
    unsigned short tmp[8];
    #pragma unroll
    for (int j = 0; j < 8; ++j) tmp[j] = f2bf(src[(size_t)j * 256]);
    *(uint4*)(out + (size_t)idx * 8) = *(uint4*)tmp;
}

// ---- one ConvLSTM step (NS = 9 for t==0, 27 otherwise) ----
template<int NS>
__global__ __launch_bounds__(512, 4)
void convlstm_step(const float* __restrict__ x,       // (B,T,64,64,32) fp32
                   const unsigned short* __restrict__ wpk,
                   const float* __restrict__ bias,    // (256)
                   const unsigned short* __restrict__ h_in, // bf16 (B,64,64,64)
                   float* __restrict__ c_st,          // fp32 (B,64,64,64) = d_out
                   unsigned short* __restrict__ h_out,// bf16 ping
                   int t, int is_last)
{
    constexpr bool HP = (NS == 27);
    constexpr int  S0 = (NS + 1) / 2;   // 14 (or 5 at t=0)

    // smem: staging (xs 8000 B + hs 14400 B) overlaid by the 72 KB exchange.
    // exchange: 64 tiles [nq(4)][mt(4)][g(4)], each 16 rows x 18 floats (pad).
    __shared__ __align__(16) unsigned char smem[64 * 288 * 4];  // 73728 B
    unsigned short* xs_s = (unsigned short*)smem;
    unsigned short* hs_s = xs_s + 4000;
    float*          ex   = (float*)smem;

    const int tid = threadIdx.x;        // 0..511
    const int gx0 = blockIdx.x * 8;
    const int gy0 = blockIdx.y * 8;
    const int b   = blockIdx.z;

    // ---- stage x halo (fp32 -> bf16), 100 px * 8 chunks ----
    {
        const float* xt = x + (((size_t)b * TSTEPS + t) * (size_t)(64 * 64 * 32));
        #pragma unroll
        for (int idx = tid; idx < 100 * 8; idx += 512) {
            int pix = idx >> 3, q = idx & 7;
            int iy = pix / 10, ix = pix - iy * 10;
            int gy = gy0 + iy - 1, gx = gx0 + ix - 1;
            unsigned short o[4] = {0, 0, 0, 0};
            if ((unsigned)gy < 64u && (unsigned)gx < 64u) {
                float4 v = *(const float4*)(xt + ((size_t)(gy * 64 + gx) * 32) + q * 4);
                o[0] = f2bf(v.x); o[1] = f2bf(v.y); o[2] = f2bf(v.z); o[3] = f2bf(v.w);
            }
            *(ushort4*)(xs_s + pix * 40 + q * 4) = *(ushort4*)o;
        }
    }
    // ---- stage h halo (bf16 copy), 100 px * 8 chunks of 8 ----
    if constexpr (HP) {
        const unsigned short* hb = h_in + ((size_t)b * (64 * 64 * 64));
        #pragma unroll
        for (int idx = tid; idx < 100 * 8; idx += 512) {
            int pix = idx >> 3, q = idx & 7;
            int iy = pix / 10, ix = pix - iy * 10;
            int gy = gy0 + iy - 1, gx = gx0 + ix - 1;
            uint4 v = make_uint4(0u, 0u, 0u, 0u);
            if ((unsigned)gy < 64u && (unsigned)gx < 64u)
                v = *(const uint4*)(hb + ((size_t)(gy * 64 + gx) * 64) + q * 8);
            *(uint4*)(hs_s + pix * 72 + q * 8) = v;
        }
    }
    __syncthreads();

    const int lane = tid & 63;
    const int wv   = tid >> 6;          // 0..7
    const int nq   = wv & 3;            // gate quadruple
    const int kh   = wv >> 2;           // K half
    const int quad = lane >> 4;
    const int m    = lane & 15;
    const int col  = m;
    const int ch   = nq * 16 + col;     // output channel 0..63

    int xb[4], hb_[4];
    #pragma unroll
    for (int mt = 0; mt < 4; ++mt) {
        int p = mt * 16 + m;
        int py = p >> 3, px = p & 7;
        xb[mt]  = (py * 10 + px) * 40 + quad * 8;
        hb_[mt] = (py * 10 + px) * 72 + quad * 8;
    }
    const unsigned short* wb = wpk + ((size_t)nq * 64 + lane) * 8;

    // acc init: kh==0 carries the bias so it is counted exactly once
    f32x4 acc[4][4];   // [mt][gate]
    #pragma unroll
    for (int g = 0; g < 4; ++g) {
        float bv = (kh == 0) ? bias[g * 64 + ch] : 0.0f;
        f32x4 bi = (f32x4){bv, bv, bv, bv};
        #pragma unroll
        for (int mt = 0; mt < 4; ++mt) acc[mt][g] = bi;
    }

    auto body = [&](int s) {
        bf16x8 a[4];
        if (s < 9) {
            int taplin = (s / 3) * 10 + (s % 3);
            #pragma unroll
            for (int mt = 0; mt < 4; ++mt)
                a[mt] = *(const bf16x8*)(xs_s + xb[mt] + taplin * 40);
        } else {
            int ss = s - 9, tap = ss >> 1, half = ss & 1;
            int taplin = (tap / 3) * 10 + (tap % 3);
            #pragma unroll
            for (int mt = 0; mt < 4; ++mt)
                a[mt] = *(const bf16x8*)(hs_s + hb_[mt] + taplin * 72 + half * 32);
        }
        #pragma unroll
        for (int g = 0; g < 4; ++g) {
            bf16x8 bf = *(const bf16x8*)(wb + (size_t)(s * 16 + 4 * g) * 512);
            #pragma unroll
            for (int mt = 0; mt < 4; ++mt)
                acc[mt][g] = __builtin_amdgcn_mfma_f32_16x16x32_bf16(a[mt], bf, acc[mt][g], 0, 0, 0);
        }
    };

    if (kh == 0) {
        #pragma unroll
        for (int s = 0; s < S0; ++s) body(s);
    } else {
        #pragma unroll
        for (int s = S0; s < NS; ++s) body(s);
    }

    // ---- cross-K reduction via LDS exchange ----
    // kh=0 writes mt {2,3} (epilogues mt {0,1}); kh=1 writes mt {0,1}.
    __syncthreads();   // staging region about to be overwritten
    {
        const int wm0 = (kh == 0) ? 2 : 0;
        #pragma unroll
        for (int mi = 0; mi < 2; ++mi) {
            int mt = wm0 + mi;
            #pragma unroll
            for (int g = 0; g < 4; ++g) {
                float* tp = ex + (((nq * 4 + mt) * 4 + g) * 288);
                #pragma unroll
                for (int r = 0; r < 4; ++r)
                    tp[(quad * 4 + r) * 18 + col] = acc[mt][g][r];
            }
        }
    }
    __syncthreads();

    // ---- reduce partner's half + epilogue for my mt pair ----
    const int km0 = (kh == 0) ? 0 : 2;
    #pragma unroll
    for (int mi = 0; mi < 2; ++mi) {
        int mt = km0 + mi;
        #pragma unroll
        for (int g = 0; g < 4; ++g) {
            const float* tp = ex + (((nq * 4 + mt) * 4 + g) * 288);
            #pragma unroll
            for (int r = 0; r < 4; ++r)
                acc[mt][g][r] += tp[(quad * 4 + r) * 18 + col];
        }
        #pragma unroll
        for (int r = 0; r < 4; ++r) {
            int p = mt * 16 + quad * 4 + r;
            int py = p >> 3, px = p & 7;
            size_t gidx = (((size_t)b * 64 + (gy0 + py)) * 64 + (gx0 + px)) * 64 + ch;
            float zi = acc[mt][0][r];
            float zf = acc[mt][1][r];
            float zc = acc[mt][2][r];
            float zo = acc[mt][3][r];
            float c_prev = HP ? c_st[gidx] : 0.0f;
            float cn = hsig(zf) * c_prev + hsig(zi) * fmaxf(zc, 0.0f);
            float hn = hsig(zo) * fmaxf(cn, 0.0f);
            if (is_last) {
                c_st[gidx] = hn;            // d_out gets final h (fp32)
            } else {
                c_st[gidx] = cn;
                h_out[gidx] = f2bf(hn);
            }
        }
    }
}

extern "C" void kernel_launch(void* const* d_in, const int* in_sizes, int n_in,
                              void* d_out, int out_size, void* d_ws, size_t ws_size,
                              hipStream_t stream) {
    const float* x  = (const float*)d_in[0];
    const float* Wg = (const float*)d_in[1];
    const float* Ug = (const float*)d_in[2];
    const float* bs = (const float*)d_in[3];

    // ws layout: [packed weights 442368 B][h0 bf16 4 MB][h1 bf16 4 MB]
    unsigned short* wpk = (unsigned short*)d_ws;
    unsigned short* h0  = (unsigned short*)((char*)d_ws + 27 * 16 * 64 * 8 * 2);
    unsigned short* h1  = h0 + (size_t)8 * 64 * 64 * 64;
    float* cS = (float*)d_out;

    prepack_w<<<108, 256, 0, stream>>>(Wg, Ug, wpk);

    dim3 grid(8, 8, 8);
    dim3 block(512);
    for (int t = 0; t < TSTEPS; ++t) {
        const unsigned short* hin = (t == 0) ? h0 : ((t & 1) ? h0 : h1);
        unsigned short* hout = (t & 1) ? h1 : h0;
        if (t == 0) {
            convlstm_step<9><<<grid, block, 0, stream>>>(x, wpk, bs, hin, cS, hout, t, 0);
        } else {
            convlstm_step<27><<<grid, block, 0, stream>>>(x, wpk, bs, hin, cS, hout,
                                                          t, (t == TSTEPS - 1) ? 1 : 0);
        }
    }
}

// Round 5
// 559.644 us; speedup vs baseline: 4.1532x; 4.1532x over previous
//
#include <hip/hip_runtime.h>

// ConvLSTM2D via MFMA implicit-GEMM. B=8,T=16,H=W=64,Cin=32,F=64,3x3 SAME.
// Round 5: GATE-split occupancy doubling (round-4 K-split spilled: 64-acc
// working set can't fit the 128-reg budget 4 waves/SIMD needs).
// 512-thread blocks, 8 waves = (nq in [0,4)) x (gh in {0,1}).
// Wave (nq,gh): M=64 px (4 M-tiles), gates {2gh, 2gh+1} for channels
// nq*16+col -> N-tiles {8gh+nq, 8gh+4+nq}. acc = 4x2 f32x4 = 32 regs.
// Per-CU B traffic unchanged (each gate's weights read by exactly one wave);
// A LDS reads double (M shared) but stay under the MFMA floor.
// Epilogue: gh=0 epilogues px 0..31 (mt 0,1), gh=1 px 32..63 (mt 2,3);
// the missing 2 gates come from a padded LDS exchange (2-way banks = free).
// Bias folded into acc init (each gate initialized by exactly one wave).
//
// Weights prepacked to B-frag order [s(27)][nt(16)][lane(64)][8] (442 KB,
// L2-resident). h ping-pongs bf16 in ws; c-state fp32 in d_out (t=15
// epilogue replaces c with final h, same-lane RMW).

#define TSTEPS 16

typedef short bf16x8 __attribute__((ext_vector_type(8)));
typedef float f32x4 __attribute__((ext_vector_type(4)));

__device__ __forceinline__ float hsig(float x) {
    return fminf(fmaxf((x + 3.0f) * (1.0f / 6.0f), 0.0f), 1.0f);
}

__device__ __forceinline__ unsigned short f2bf(float f) {
    union { float f; unsigned int u; } v; v.f = f;
    unsigned int r = v.u + 0x7fffu + ((v.u >> 16) & 1u);  // RNE
    return (unsigned short)(r >> 16);
}

// ---- weight prepack: Wg(3,3,32,256), Ug(3,3,64,256) fp32 -> bf16 B-frags ----
__global__ __launch_bounds__(256)
void prepack_w(const float* __restrict__ Wg, const float* __restrict__ Ug,
               unsigned short* __restrict__ out)
{
    int idx = blockIdx.x * 256 + threadIdx.x;   // 27*16*64 = 27648
    if (idx >= 27648) return;
    int lane = idx & 63;
    int nt   = (idx >> 6) & 15;
    int s    = idx >> 10;
    int col = lane & 15, quad = lane >> 4;
    int n = nt * 16 + col;
    int k0 = quad * 8;
    const float* src;
    if (s < 9) {
        src = Wg + ((size_t)s * 32 + k0) * 256 + n;
    } else {
        int ss = s - 9; int tap = ss >> 1; int half = ss & 1;
        src = Ug + ((size_t)tap * 64 + half * 32 + k0) * 256 + n;
    }
    unsigned short tmp[8];
    #pragma unroll
    for (int j = 0; j < 8; ++j) tmp[j] = f2bf(src[(size_t)j * 256]);
    *(uint4*)(out + (size_t)idx * 8) = *(uint4*)tmp;
}

// ---- one ConvLSTM step (NS = 9 for t==0, 27 otherwise) ----
template<int NS>
__global__ __launch_bounds__(512, 2)
void convlstm_step(const float* __restrict__ x,       // (B,T,64,64,32) fp32
                   const unsigned short* __restrict__ wpk,
                   const float* __restrict__ bias,    // (256)
                   const unsigned short* __restrict__ h_in, // bf16 (B,64,64,64)
                   float* __restrict__ c_st,          // fp32 (B,64,64,64) = d_out
                   unsigned short* __restrict__ h_out,// bf16 ping
                   int t, int is_last)
{
    constexpr bool HP = (NS == 27);

    // smem: staging (xs 8000 B + hs 14400 B = 22400 B) overlaid by the
    // gate-exchange: 32 tiles [nq(4)][mt(4)][gi(2)] x 16 rows x 18 floats.
    __shared__ __align__(16) unsigned char smem[32 * 288 * 4];  // 36864 B
    unsigned short* xs_s = (unsigned short*)smem;
    unsigned short* hs_s = xs_s + 4000;
    float*          ex   = (float*)smem;

    const int tid = threadIdx.x;        // 0..511
    const int gx0 = blockIdx.x * 8;
    const int gy0 = blockIdx.y * 8;
    const int b   = blockIdx.z;

    // ---- stage x halo (fp32 -> bf16), 100 px * 8 chunks ----
    {
        const float* xt = x + (((size_t)b * TSTEPS + t) * (size_t)(64 * 64 * 32));
        #pragma unroll
        for (int idx = tid; idx < 100 * 8; idx += 512) {
            int pix = idx >> 3, q = idx & 7;
            int iy = pix / 10, ix = pix - iy * 10;
            int gy = gy0 + iy - 1, gx = gx0 + ix - 1;
            unsigned short o[4] = {0, 0, 0, 0};
            if ((unsigned)gy < 64u && (unsigned)gx < 64u) {
                float4 v = *(const float4*)(xt + ((size_t)(gy * 64 + gx) * 32) + q * 4);
                o[0] = f2bf(v.x); o[1] = f2bf(v.y); o[2] = f2bf(v.z); o[3] = f2bf(v.w);
            }
            *(ushort4*)(xs_s + pix * 40 + q * 4) = *(ushort4*)o;
        }
    }
    // ---- stage h halo (bf16 copy) ----
    if constexpr (HP) {
        const unsigned short* hb = h_in + ((size_t)b * (64 * 64 * 64));
        #pragma unroll
        for (int idx = tid; idx < 100 * 8; idx += 512) {
            int pix = idx >> 3, q = idx & 7;
            int iy = pix / 10, ix = pix - iy * 10;
            int gy = gy0 + iy - 1, gx = gx0 + ix - 1;
            uint4 v = make_uint4(0u, 0u, 0u, 0u);
            if ((unsigned)gy < 64u && (unsigned)gx < 64u)
                v = *(const uint4*)(hb + ((size_t)(gy * 64 + gx) * 64) + q * 8);
            *(uint4*)(hs_s + pix * 72 + q * 8) = v;
        }
    }
    __syncthreads();

    const int lane = tid & 63;
    const int wv   = tid >> 6;          // 0..7
    const int nq   = wv & 3;            // channel quadruple (16 channels)
    const int gh   = wv >> 2;           // gate half: 0 -> {i,f}, 1 -> {c,o}
    const int quad = lane >> 4;
    const int m    = lane & 15;
    const int col  = m;
    const int ch   = nq * 16 + col;     // output channel 0..63

    int xb[4], hb_[4];
    #pragma unroll
    for (int mt = 0; mt < 4; ++mt) {
        int p = mt * 16 + m;
        int py = p >> 3, px = p & 7;
        xb[mt]  = (py * 10 + px) * 40 + quad * 8;
        hb_[mt] = (py * 10 + px) * 72 + quad * 8;
    }
    // B-frag N-tiles: nt(gi) = 8*gh + 4*gi + nq
    const unsigned short* wb = wpk + ((size_t)(8 * gh + nq) * 64 + lane) * 8;

    // acc init = bias for this wave's two gates (each gate init'd by one wave)
    f32x4 acc[4][2];   // [mt][gi]
    #pragma unroll
    for (int gi = 0; gi < 2; ++gi) {
        float bv = bias[(2 * gh + gi) * 64 + ch];
        f32x4 bi = (f32x4){bv, bv, bv, bv};
        #pragma unroll
        for (int mt = 0; mt < 4; ++mt) acc[mt][gi] = bi;
    }

    // ---- K-loop: 4 A-loads + 2 B-loads + 8 MFMA per k-step ----
    #pragma unroll
    for (int s = 0; s < NS; ++s) {
        bf16x8 a[4];
        if (s < 9) {
            int taplin = (s / 3) * 10 + (s % 3);
            #pragma unroll
            for (int mt = 0; mt < 4; ++mt)
                a[mt] = *(const bf16x8*)(xs_s + xb[mt] + taplin * 40);
        } else {
            int ss = s - 9, tap = ss >> 1, half = ss & 1;
            int taplin = (tap / 3) * 10 + (tap % 3);
            #pragma unroll
            for (int mt = 0; mt < 4; ++mt)
                a[mt] = *(const bf16x8*)(hs_s + hb_[mt] + taplin * 72 + half * 32);
        }
        #pragma unroll
        for (int gi = 0; gi < 2; ++gi) {
            bf16x8 bf = *(const bf16x8*)(wb + (size_t)(s * 16 + 4 * gi) * 512);
            #pragma unroll
            for (int mt = 0; mt < 4; ++mt)
                acc[mt][gi] = __builtin_amdgcn_mfma_f32_16x16x32_bf16(a[mt], bf, acc[mt][gi], 0, 0, 0);
        }
    }

    // ---- gate exchange via LDS ----
    // gh=0 epilogues mt {0,1} (px 0..31), writes its mt {2,3}.
    // gh=1 epilogues mt {2,3} (px 32..63), writes its mt {0,1}.
    __syncthreads();   // staging region about to be overwritten
    {
        const int wm0 = (gh == 0) ? 2 : 0;
        #pragma unroll
        for (int mi = 0; mi < 2; ++mi) {
            int mt = wm0 + mi;
            #pragma unroll
            for (int gi = 0; gi < 2; ++gi) {
                float* tp = ex + (((nq * 4 + mt) * 2 + gi) * 288);
                #pragma unroll
                for (int r = 0; r < 4; ++r)
                    tp[(quad * 4 + r) * 18 + col] = acc[mt][gi][r];
            }
        }
    }
    __syncthreads();

    // ---- epilogue for my mt pair ----
    const int em0 = (gh == 0) ? 0 : 2;
    #pragma unroll
    for (int mi = 0; mi < 2; ++mi) {
        int mt = em0 + mi;
        const float* tp0 = ex + (((nq * 4 + mt) * 2 + 0) * 288);
        const float* tp1 = ex + (((nq * 4 + mt) * 2 + 1) * 288);
        #pragma unroll
        for (int r = 0; r < 4; ++r) {
            int row = (quad * 4 + r) * 18 + col;
            float zi, zf, zc, zo;
            if (gh == 0) {               // own i,f; partner's c,o in LDS
                zi = acc[mt][0][r];
                zf = acc[mt][1][r];
                zc = tp0[row];
                zo = tp1[row];
            } else {                     // partner's i,f in LDS; own c,o
                zi = tp0[row];
                zf = tp1[row];
                zc = acc[mt][0][r];
                zo = acc[mt][1][r];
            }
            int p = mt * 16 + quad * 4 + r;
            int py = p >> 3, px = p & 7;
            size_t gidx = (((size_t)b * 64 + (gy0 + py)) * 64 + (gx0 + px)) * 64 + ch;
            float c_prev = HP ? c_st[gidx] : 0.0f;
            float cn = hsig(zf) * c_prev + hsig(zi) * fmaxf(zc, 0.0f);
            float hn = hsig(zo) * fmaxf(cn, 0.0f);
            if (is_last) {
                c_st[gidx] = hn;            // d_out gets final h (fp32)
            } else {
                c_st[gidx] = cn;
                h_out[gidx] = f2bf(hn);
            }
        }
    }
}

extern "C" void kernel_launch(void* const* d_in, const int* in_sizes, int n_in,
                              void* d_out, int out_size, void* d_ws, size_t ws_size,
                              hipStream_t stream) {
    const float* x  = (const float*)d_in[0];
    const float* Wg = (const float*)d_in[1];
    const float* Ug = (const float*)d_in[2];
    const float* bs = (const float*)d_in[3];

    // ws layout: [packed weights 442368 B][h0 bf16 4 MB][h1 bf16 4 MB]
    unsigned short* wpk = (unsigned short*)d_ws;
    unsigned short* h0  = (unsigned short*)((char*)d_ws + 27 * 16 * 64 * 8 * 2);
    unsigned short* h1  = h0 + (size_t)8 * 64 * 64 * 64;
    float* cS = (float*)d_out;

    prepack_w<<<108, 256, 0, stream>>>(Wg, Ug, wpk);

    dim3 grid(8, 8, 8);
    dim3 block(512);
    for (int t = 0; t < TSTEPS; ++t) {
        const unsigned short* hin = (t == 0) ? h0 : ((t & 1) ? h0 : h1);
        unsigned short* hout = (t & 1) ? h1 : h0;
        if (t == 0) {
            convlstm_step<9><<<grid, block, 0, stream>>>(x, wpk, bs, hin, cS, hout, t, 0);
        } else {
            convlstm_step<27><<<grid, block, 0, stream>>>(x, wpk, bs, hin, cS, hout,
                                                          t, (t == TSTEPS - 1) ? 1 : 0);
        }
    }
}

// Round 6
// 482.035 us; speedup vs baseline: 4.8219x; 1.1610x over previous
//
#include <hip/hip_runtime.h>

// ConvLSTM2D via MFMA implicit-GEMM. B=8,T=16,H=W=64,Cin=32,F=64,3x3 SAME.
// Round 6: R2 structure (best: 486us) + amdgpu_waves_per_eu(2,2).
// Grid caps occupancy at 2 waves/SIMD (512 blocks = 2 blocks/CU), so VGPRs
// up to 256 are free; the attribute pins the scheduler's occupancy model to
// exactly 2 waves/EU so it stops minimizing pressure (R2: 88 VGPR, R3: 72 —
// loads sunk to uses, latency-bound at ~30us/step vs ~7-9us overlapped floor)
// and hoists the unrolled K-loop's L2 B-loads / LDS A-reads itself.
//
// Per block: 8x8 px tile x 256 z-ch, 4 waves. Wave w owns N-tiles
// {w,w+4,w+8,w+12} -> gates i/f/c/o for channel w*16+col land in the same
// lane/reg across the 4 tile-groups (shuffle-free epilogue).
// A (x-halo 10x10x32 + h-halo 10x10x64) in LDS bf16, padded strides 40/72
// (2-way bank aliasing = free). Weights prepacked to B-frag order
// [s(27)][nt(16)][lane(64)][8] (442 KB, L2-resident).
// h ping-pongs bf16 in ws; c-state fp32 in d_out (t=15 writes final h).

#define TSTEPS 16

typedef short bf16x8 __attribute__((ext_vector_type(8)));
typedef float f32x4 __attribute__((ext_vector_type(4)));

__device__ __forceinline__ float hsig(float x) {
    return fminf(fmaxf((x + 3.0f) * (1.0f / 6.0f), 0.0f), 1.0f);
}

__device__ __forceinline__ unsigned short f2bf(float f) {
    union { float f; unsigned int u; } v; v.f = f;
    unsigned int r = v.u + 0x7fffu + ((v.u >> 16) & 1u);  // RNE
    return (unsigned short)(r >> 16);
}

// ---- weight prepack: Wg(3,3,32,256), Ug(3,3,64,256) fp32 -> bf16 B-frags ----
__global__ __launch_bounds__(256)
void prepack_w(const float* __restrict__ Wg, const float* __restrict__ Ug,
               unsigned short* __restrict__ out)
{
    int idx = blockIdx.x * 256 + threadIdx.x;   // 27*16*64 = 27648
    if (idx >= 27648) return;
    int lane = idx & 63;
    int nt   = (idx >> 6) & 15;
    int s    = idx >> 10;
    int col = lane & 15, quad = lane >> 4;
    int n = nt * 16 + col;
    int k0 = quad * 8;
    const float* src;
    if (s < 9) {
        src = Wg + ((size_t)s * 32 + k0) * 256 + n;
    } else {
        int ss = s - 9; int tap = ss >> 1; int half = ss & 1;
        src = Ug + ((size_t)tap * 64 + half * 32 + k0) * 256 + n;
    }
    unsigned short tmp[8];
    #pragma unroll
    for (int j = 0; j < 8; ++j) tmp[j] = f2bf(src[(size_t)j * 256]);
    *(uint4*)(out + (size_t)idx * 8) = *(uint4*)tmp;
}

// ---- one ConvLSTM step (NS = 9 for t==0, 27 otherwise) ----
template<int NS>
__global__ __launch_bounds__(256)
__attribute__((amdgpu_waves_per_eu(2, 2)))
void convlstm_step(const float* __restrict__ x,       // (B,T,64,64,32) fp32
                   const unsigned short* __restrict__ wpk,
                   const float* __restrict__ bias,    // (256)
                   const unsigned short* __restrict__ h_in, // bf16 (B,64,64,64)
                   float* __restrict__ c_st,          // fp32 (B,64,64,64) = d_out
                   unsigned short* __restrict__ h_out,// bf16 ping
                   int t, int is_last)
{
    constexpr bool HP = (NS == 27);
    __shared__ __align__(16) unsigned short xs_s[100 * 40];           // 8.0 KB
    __shared__ __align__(16) unsigned short hs_s[HP ? 100 * 72 : 8];  // 14.4 KB

    const int tid = threadIdx.x;
    const int gx0 = blockIdx.x * 8;
    const int gy0 = blockIdx.y * 8;
    const int b   = blockIdx.z;

    // ---- stage x halo (fp32 -> bf16) ----
    {
        const float* xt = x + (((size_t)b * TSTEPS + t) * (size_t)(64 * 64 * 32));
        #pragma unroll 4
        for (int idx = tid; idx < 100 * 8; idx += 256) {
            int pix = idx >> 3, q = idx & 7;
            int iy = pix / 10, ix = pix - iy * 10;
            int gy = gy0 + iy - 1, gx = gx0 + ix - 1;
            unsigned short o[4] = {0, 0, 0, 0};
            if ((unsigned)gy < 64u && (unsigned)gx < 64u) {
                float4 v = *(const float4*)(xt + ((size_t)(gy * 64 + gx) * 32) + q * 4);
                o[0] = f2bf(v.x); o[1] = f2bf(v.y); o[2] = f2bf(v.z); o[3] = f2bf(v.w);
            }
            *(ushort4*)(xs_s + pix * 40 + q * 4) = *(ushort4*)o;
        }
    }
    // ---- stage h halo (bf16 copy) ----
    if constexpr (HP) {
        const unsigned short* hb = h_in + ((size_t)b * (64 * 64 * 64));
        #pragma unroll 4
        for (int idx = tid; idx < 100 * 8; idx += 256) {
            int pix = idx >> 3, q = idx & 7;
            int iy = pix / 10, ix = pix - iy * 10;
            int gy = gy0 + iy - 1, gx = gx0 + ix - 1;
            uint4 v = make_uint4(0u, 0u, 0u, 0u);
            if ((unsigned)gy < 64u && (unsigned)gx < 64u)
                v = *(const uint4*)(hb + ((size_t)(gy * 64 + gx) * 64) + q * 8);
            *(uint4*)(hs_s + pix * 72 + q * 8) = v;
        }
    }
    __syncthreads();

    const int lane = tid & 63;
    const int w    = tid >> 6;
    const int quad = lane >> 4;
    const int m    = lane & 15;
    const int col  = m;
    const int ch   = w * 16 + col;   // output channel 0..63

    int xb[4], hb_[4];
    #pragma unroll
    for (int mt = 0; mt < 4; ++mt) {
        int p = mt * 16 + m;
        int py = p >> 3, px = p & 7;
        xb[mt]  = (py * 10 + px) * 40 + quad * 8;
        hb_[mt] = (py * 10 + px) * 72 + quad * 8;
    }
    const unsigned short* wb = wpk + ((size_t)w * 64 + lane) * 8;

    // acc init = bias
    f32x4 acc[4][4];   // [mt][gate]
    #pragma unroll
    for (int g = 0; g < 4; ++g) {
        float bv = bias[g * 64 + ch];
        f32x4 bi = (f32x4){bv, bv, bv, bv};
        #pragma unroll
        for (int mt = 0; mt < 4; ++mt) acc[mt][g] = bi;
    }

    // ---- K-loop: fully unrolled; loads at use, scheduler hoists under
    // the pinned 2-waves/EU budget (VGPRs up to 256 are free) ----
    #pragma unroll
    for (int s = 0; s < NS; ++s) {
        bf16x8 a[4];
        if (s < 9) {
            int taplin = (s / 3) * 10 + (s % 3);
            #pragma unroll
            for (int mt = 0; mt < 4; ++mt)
                a[mt] = *(const bf16x8*)(xs_s + xb[mt] + taplin * 40);
        } else {
            int ss = s - 9, tap = ss >> 1, half = ss & 1;
            int taplin = (tap / 3) * 10 + (tap % 3);
            #pragma unroll
            for (int mt = 0; mt < 4; ++mt)
                a[mt] = *(const bf16x8*)(hs_s + hb_[mt] + taplin * 72 + half * 32);
        }
        #pragma unroll
        for (int g = 0; g < 4; ++g) {
            bf16x8 bf = *(const bf16x8*)(wb + (size_t)(s * 16 + 4 * g) * 512);
            #pragma unroll
            for (int mt = 0; mt < 4; ++mt)
                acc[mt][g] = __builtin_amdgcn_mfma_f32_16x16x32_bf16(a[mt], bf, acc[mt][g], 0, 0, 0);
        }
    }

    // ---- epilogue: gates + state update ----
    // C/D layout: col = lane&15 (channel), row = quad*4 + r (pixel)
    #pragma unroll
    for (int mt = 0; mt < 4; ++mt) {
        #pragma unroll
        for (int r = 0; r < 4; ++r) {
            int p = mt * 16 + quad * 4 + r;
            int py = p >> 3, px = p & 7;
            size_t gidx = (((size_t)b * 64 + (gy0 + py)) * 64 + (gx0 + px)) * 64 + ch;
            float zi = acc[mt][0][r];
            float zf = acc[mt][1][r];
            float zc = acc[mt][2][r];
            float zo = acc[mt][3][r];
            float c_prev = HP ? c_st[gidx] : 0.0f;
            float cn = hsig(zf) * c_prev + hsig(zi) * fmaxf(zc, 0.0f);
            float hn = hsig(zo) * fmaxf(cn, 0.0f);
            if (is_last) {
                c_st[gidx] = hn;            // d_out gets final h (fp32)
            } else {
                c_st[gidx] = cn;
                h_out[gidx] = f2bf(hn);
            }
        }
    }
}

extern "C" void kernel_launch(void* const* d_in, const int* in_sizes, int n_in,
                              void* d_out, int out_size, void* d_ws, size_t ws_size,
                              hipStream_t stream) {
    const float* x  = (const float*)d_in[0];
    const float* Wg = (const float*)d_in[1];
    const float* Ug = (const float*)d_in[2];
    const float* bs = (const float*)d_in[3];

    // ws layout: [packed weights 442368 B][h0 bf16 4 MB][h1 bf16 4 MB]
    unsigned short* wpk = (unsigned short*)d_ws;
    unsigned short* h0  = (unsigned short*)((char*)d_ws + 27 * 16 * 64 * 8 * 2);
    unsigned short* h1  = h0 + (size_t)8 * 64 * 64 * 64;
    float* cS = (float*)d_out;

    prepack_w<<<108, 256, 0, stream>>>(Wg, Ug, wpk);

    dim3 grid(8, 8, 8);
    dim3 block(256);
    for (int t = 0; t < TSTEPS; ++t) {
        const unsigned short* hin = (t == 0) ? h0 : ((t & 1) ? h0 : h1);
        unsigned short* hout = (t & 1) ? h1 : h0;
        if (t == 0) {
            convlstm_step<9><<<grid, block, 0, stream>>>(x, wpk, bs, hin, cS, hout, t, 0);
        } else {
            convlstm_step<27><<<grid, block, 0, stream>>>(x, wpk, bs, hin, cS, hout,
                                                          t, (t == TSTEPS - 1) ? 1 : 0);
        }
    }
}

// Round 7
// 472.305 us; speedup vs baseline: 4.9212x; 1.0206x over previous
//
#include <hip/hip_runtime.h>

// ConvLSTM2D via MFMA implicit-GEMM. B=8,T=16,H=W=64,Cin=32,F=64,3x3 SAME.
// Round 7: AITER-style K-loop. B-fragments stream global->LDS via
// global_load_lds_dwordx4 into a 3-slot ring (16 KB/slot, wave-private
// nt sub-regions -> NO barrier in the K-loop), consumed with fine-grained
// s_waitcnt vmcnt(8/4/0) -- loads for steps s+1,s+2 stay in flight while
// step s computes. B never round-trips through VGPRs, so the compiler's
// register-pressure heuristic (which defeated R3/R6 hoisting) is moot.
//
// Per block: 8x8 px tile x 256 z-ch, 4 waves. Wave w owns n-tiles
// {w,w+4,w+8,w+12} -> gates i/f/c/o for channel w*16+col in the same
// lane/reg (shuffle-free epilogue). A halos in LDS bf16 (pad 40/72).
// Weights prepacked [s(27)][nt(16)][lane(64)][8] = wave-uniform-base +
// lane*16 DMA pattern. h ping-pongs bf16 in ws; c fp32 in d_out.

#define TSTEPS 16

typedef short bf16x8 __attribute__((ext_vector_type(8)));
typedef float f32x4 __attribute__((ext_vector_type(4)));
typedef unsigned int __attribute__((address_space(1))) gu32;
typedef unsigned int __attribute__((address_space(3))) lu32;

__device__ __forceinline__ float hsig(float x) {
    return fminf(fmaxf((x + 3.0f) * (1.0f / 6.0f), 0.0f), 1.0f);
}

__device__ __forceinline__ unsigned short f2bf(float f) {
    union { float f; unsigned int u; } v; v.f = f;
    unsigned int r = v.u + 0x7fffu + ((v.u >> 16) & 1u);  // RNE
    return (unsigned short)(r >> 16);
}

// ---- weight prepack: Wg(3,3,32,256), Ug(3,3,64,256) fp32 -> bf16 B-frags ----
__global__ __launch_bounds__(256)
void prepack_w(const float* __restrict__ Wg, const float* __restrict__ Ug,
               unsigned short* __restrict__ out)
{
    int idx = blockIdx.x * 256 + threadIdx.x;   // 27*16*64 = 27648
    if (idx >= 27648) return;
    int lane = idx & 63;
    int nt   = (idx >> 6) & 15;
    int s    = idx >> 10;
    int col = lane & 15, quad = lane >> 4;
    int n = nt * 16 + col;
    int k0 = quad * 8;
    const float* src;
    if (s < 9) {
        src = Wg + ((size_t)s * 32 + k0) * 256 + n;
    } else {
        int ss = s - 9; int tap = ss >> 1; int half = ss & 1;
        src = Ug + ((size_t)tap * 64 + half * 32 + k0) * 256 + n;
    }
    unsigned short tmp[8];
    #pragma unroll
    for (int j = 0; j < 8; ++j) tmp[j] = f2bf(src[(size_t)j * 256]);
    *(uint4*)(out + (size_t)idx * 8) = *(uint4*)tmp;
}

// ---- one ConvLSTM step (NS = 9 for t==0, 27 otherwise) ----
template<int NS>
__global__ __launch_bounds__(256)
__attribute__((amdgpu_waves_per_eu(2, 2)))
void convlstm_step(const float* __restrict__ x,       // (B,T,64,64,32) fp32
                   const unsigned short* __restrict__ wpk,
                   const float* __restrict__ bias,    // (256)
                   const unsigned short* __restrict__ h_in, // bf16 (B,64,64,64)
                   float* __restrict__ c_st,          // fp32 (B,64,64,64) = d_out
                   unsigned short* __restrict__ h_out,// bf16 ping
                   int t, int is_last)
{
    constexpr bool HP = (NS == 27);
    constexpr int  P  = 3;   // B ring depth (k-steps in flight)

    __shared__ __align__(16) unsigned short xs_s[100 * 40];           // 8.0 KB
    __shared__ __align__(16) unsigned short hs_s[HP ? 100 * 72 : 8];  // 14.4 KB
    __shared__ __align__(16) unsigned short bring[P * 16 * 512];      // 49.2 KB

    const int tid = threadIdx.x;
    const int gx0 = blockIdx.x * 8;
    const int gy0 = blockIdx.y * 8;
    const int b   = blockIdx.z;

    // ---- stage x halo (fp32 -> bf16) ----
    {
        const float* xt = x + (((size_t)b * TSTEPS + t) * (size_t)(64 * 64 * 32));
        #pragma unroll 4
        for (int idx = tid; idx < 100 * 8; idx += 256) {
            int pix = idx >> 3, q = idx & 7;
            int iy = pix / 10, ix = pix - iy * 10;
            int gy = gy0 + iy - 1, gx = gx0 + ix - 1;
            unsigned short o[4] = {0, 0, 0, 0};
            if ((unsigned)gy < 64u && (unsigned)gx < 64u) {
                float4 v = *(const float4*)(xt + ((size_t)(gy * 64 + gx) * 32) + q * 4);
                o[0] = f2bf(v.x); o[1] = f2bf(v.y); o[2] = f2bf(v.z); o[3] = f2bf(v.w);
            }
            *(ushort4*)(xs_s + pix * 40 + q * 4) = *(ushort4*)o;
        }
    }
    // ---- stage h halo (bf16 copy) ----
    if constexpr (HP) {
        const unsigned short* hb = h_in + ((size_t)b * (64 * 64 * 64));
        #pragma unroll 4
        for (int idx = tid; idx < 100 * 8; idx += 256) {
            int pix = idx >> 3, q = idx & 7;
            int iy = pix / 10, ix = pix - iy * 10;
            int gy = gy0 + iy - 1, gx = gx0 + ix - 1;
            uint4 v = make_uint4(0u, 0u, 0u, 0u);
            if ((unsigned)gy < 64u && (unsigned)gx < 64u)
                v = *(const uint4*)(hb + ((size_t)(gy * 64 + gx) * 64) + q * 8);
            *(uint4*)(hs_s + pix * 72 + q * 8) = v;
        }
    }
    __syncthreads();   // staging visible; also drains staging vmcnt

    const int lane = tid & 63;
    const int w    = tid >> 6;
    const int quad = lane >> 4;
    const int m    = lane & 15;
    const int col  = m;
    const int ch   = w * 16 + col;   // output channel 0..63

    int xb[4], hb_[4];
    #pragma unroll
    for (int mt = 0; mt < 4; ++mt) {
        int p = mt * 16 + m;
        int py = p >> 3, px = p & 7;
        xb[mt]  = (py * 10 + px) * 40 + quad * 8;
        hb_[mt] = (py * 10 + px) * 72 + quad * 8;
    }

    // ---- B DMA: wave w streams its 4 n-tiles for k-step s into slot s%P.
    // Layout is wave-uniform LDS base + lane*16 (the global_load_lds shape).
    auto issueDMA = [&](int s) {
        int slot = s % P;
        #pragma unroll
        for (int g = 0; g < 4; ++g) {
            int nt = w + 4 * g;
            const unsigned short* gp = wpk + ((size_t)(s * 16 + nt) * 64 + lane) * 8;
            unsigned short* lp = bring + ((size_t)slot * 16 + nt) * 512;  // uniform
            __builtin_amdgcn_global_load_lds((const gu32*)gp, (lu32*)lp, 16, 0, 0);
        }
    };

    // acc init = bias
    f32x4 acc[4][4];   // [mt][gate]
    #pragma unroll
    for (int g = 0; g < 4; ++g) {
        float bv = bias[g * 64 + ch];
        f32x4 bi = (f32x4){bv, bv, bv, bv};
        #pragma unroll
        for (int mt = 0; mt < 4; ++mt) acc[mt][g] = bi;
    }

    // ---- prologue: fill the ring ----
    issueDMA(0);
    issueDMA(1);
    issueDMA(2);

    // ---- K-loop: vmcnt-gated, barrier-free ----
    #pragma unroll
    for (int s = 0; s < NS; ++s) {
        // wait for MY slot-s loads; keep s+1,s+2 in flight (never vmcnt(0)
        // except the last step). imm: vmcnt in [3:0], exp=7, lgkm=15.
        if (s + 2 < NS)      __builtin_amdgcn_s_waitcnt(0xF78);  // vmcnt(8)
        else if (s + 1 < NS) __builtin_amdgcn_s_waitcnt(0xF74);  // vmcnt(4)
        else                 __builtin_amdgcn_s_waitcnt(0xF70);  // vmcnt(0)

        const int slot = s % P;
        bf16x8 bfr[4];
        #pragma unroll
        for (int g = 0; g < 4; ++g)
            bfr[g] = *(const bf16x8*)(bring + ((size_t)slot * 16 + (w + 4 * g)) * 512 + lane * 8);

        bf16x8 a[4];
        if (s < 9) {
            int taplin = (s / 3) * 10 + (s % 3);
            #pragma unroll
            for (int mt = 0; mt < 4; ++mt)
                a[mt] = *(const bf16x8*)(xs_s + xb[mt] + taplin * 40);
        } else {
            int ss = s - 9, tap = ss >> 1, half = ss & 1;
            int taplin = (tap / 3) * 10 + (tap % 3);
            #pragma unroll
            for (int mt = 0; mt < 4; ++mt)
                a[mt] = *(const bf16x8*)(hs_s + hb_[mt] + taplin * 72 + half * 32);
        }

        #pragma unroll
        for (int g = 0; g < 4; ++g)
            #pragma unroll
            for (int mt = 0; mt < 4; ++mt)
                acc[mt][g] = __builtin_amdgcn_mfma_f32_16x16x32_bf16(a[mt], bfr[g], acc[mt][g], 0, 0, 0);

        // refill the slot we just consumed (after the MFMAs that read it;
        // compiler's lgkm waits for the MFMA operands order the ds_reads
        // ahead of this LDS write)
        if (s + P < NS) issueDMA(s + P);
    }

    // ---- epilogue: gates + state update ----
    // C/D layout: col = lane&15 (channel), row = quad*4 + r (pixel)
    #pragma unroll
    for (int mt = 0; mt < 4; ++mt) {
        #pragma unroll
        for (int r = 0; r < 4; ++r) {
            int p = mt * 16 + quad * 4 + r;
            int py = p >> 3, px = p & 7;
            size_t gidx = (((size_t)b * 64 + (gy0 + py)) * 64 + (gx0 + px)) * 64 + ch;
            float zi = acc[mt][0][r];
            float zf = acc[mt][1][r];
            float zc = acc[mt][2][r];
            float zo = acc[mt][3][r];
            float c_prev = HP ? c_st[gidx] : 0.0f;
            float cn = hsig(zf) * c_prev + hsig(zi) * fmaxf(zc, 0.0f);
            float hn = hsig(zo) * fmaxf(cn, 0.0f);
            if (is_last) {
                c_st[gidx] = hn;            // d_out gets final h (fp32)
            } else {
                c_st[gidx] = cn;
                h_out[gidx] = f2bf(hn);
            }
        }
    }
}

extern "C" void kernel_launch(void* const* d_in, const int* in_sizes, int n_in,
                              void* d_out, int out_size, void* d_ws, size_t ws_size,
                              hipStream_t stream) {
    const float* x  = (const float*)d_in[0];
    const float* Wg = (const float*)d_in[1];
    const float* Ug = (const float*)d_in[2];
    const float* bs = (const float*)d_in[3];

    // ws layout: [packed weights 442368 B][h0 bf16 4 MB][h1 bf16 4 MB]
    unsigned short* wpk = (unsigned short*)d_ws;
    unsigned short* h0  = (unsigned short*)((char*)d_ws + 27 * 16 * 64 * 8 * 2);
    unsigned short* h1  = h0 + (size_t)8 * 64 * 64 * 64;
    float* cS = (float*)d_out;

    prepack_w<<<108, 256, 0, stream>>>(Wg, Ug, wpk);

    dim3 grid(8, 8, 8);
    dim3 block(256);
    for (int t = 0; t < TSTEPS; ++t) {
        const unsigned short* hin = (t == 0) ? h0 : ((t & 1) ? h0 : h1);
        unsigned short* hout = (t & 1) ? h1 : h0;
        if (t == 0) {
            convlstm_step<9><<<grid, block, 0, stream>>>(x, wpk, bs, hin, cS, hout, t, 0);
        } else {
            convlstm_step<27><<<grid, block, 0, stream>>>(x, wpk, bs, hin, cS, hout,
                                                          t, (t == TSTEPS - 1) ? 1 : 0);
        }
    }
}